// Round 20
// baseline (81.787 us; speedup 1.0000x reference)
//
#include <hip/hip_runtime.h>
#include <stdint.h>

#define Bc 32768
#define NSTAG 2048383
#define NFULL 2097152
#define P_TOTAL (13*Bc)   // 425984 = 13312 * 32 (only the 6+6 USED stencil points)

typedef short  short8_t __attribute__((ext_vector_type(8)));
typedef __bf16 bf16x8_t __attribute__((ext_vector_type(8)));
typedef __bf16 bf16x4_t __attribute__((ext_vector_type(4)));
typedef float  f32x4_t  __attribute__((ext_vector_type(4)));

#if __has_builtin(__builtin_amdgcn_exp2f)
#define EXP2F(x) __builtin_amdgcn_exp2f(x)
#else
#define EXP2F(x) exp2f(x)
#endif
#if __has_builtin(__builtin_amdgcn_rcpf)
#define RCPF(x) __builtin_amdgcn_rcpf(x)
#else
#define RCPF(x) (1.0f/(x))
#endif

// tanh(x) = 1 - 2/(e^{2x}+1); e^{2x} = 2^(x*2*log2 e). 5 insts, exact at +-inf.
__device__ __forceinline__ float fast_tanh(float x){
  float e = EXP2F(x * 2.885390081777927f);
  return fmaf(-2.0f, RCPF(e + 1.0f), 1.0f);
}

__device__ __forceinline__ short f2bf(float f){
  union { float f; unsigned u; } v; v.f = f;
  unsigned r = v.u + 0x7FFFu + ((v.u >> 16) & 1u);   // RNE
  return (short)(r >> 16);
}

// ---- weight convert to FRAGMENT-MAJOR bf16 (A-operand mapping):
// W2f/W3f CT-MAJOR: f = ct*4+kk, Wf[f*512 + lane*8 + u] = bf16(W[k][j]),
// j = ct*16+(lane&15), k = kk*32+(lane>>4)*8+u  (4 kk-frags of a ct contiguous).
// W1f: K=4 augmented ([W1;b1;0...], f=ct, 8 KB).  W4f: A-row 0 = W4[k], f=kk.
__global__ void lap_convert_w(const float* __restrict__ W1, const float* __restrict__ b1,
                              const float* __restrict__ W2, const float* __restrict__ W3,
                              const float* __restrict__ W4,
                              short* __restrict__ W1f, short* __restrict__ W2f,
                              short* __restrict__ W3f, short* __restrict__ W4f){
  int o = blockIdx.x * 256 + threadIdx.x;      // 0..38911
  if (o < 4096) {
    int e = o;
    int u = e & 7, lane = (e >> 3) & 63, ct = (e >> 9) & 7;
    int j = ct*16 + (lane & 15);
    int k = (lane >> 4)*8 + u;
    float v = (k < 3) ? W1[k*128 + j] : ((k == 3) ? b1[j] : 0.f);
    W1f[e] = f2bf(v);
  } else if (o < 36864) {
    o -= 4096;
    int which = o >> 14; int e = o & 16383;
    int u = e & 7, lane = (e >> 3) & 63, ct = (e >> 9) & 7, kk = e >> 12;
    int j = ct*16 + (lane & 15);
    int k = kk*32 + (lane >> 4)*8 + u;
    const float* W = which ? W3 : W2;
    short* O = which ? W3f : W2f;
    O[(ct*4 + kk)*512 + lane*8 + u] = f2bf(W[k*128 + j]);
  } else {
    int e = o - 36864;                          // 0..2047
    int u = e & 7, lane = (e >> 3) & 63, kk = e >> 9;
    int k = kk*32 + (lane >> 4)*8 + u;
    W4f[e] = ((lane & 15) == 0) ? f2bf(W4[k]) : 0;
  }
}

// ---- main MLP kernel: ONE wave per block, 32 points, fully wave-private.
// r20 = r19 with 64-thread blocks: waves have no barriers, so block granularity
// is free. LDS 32KB -> 8KB/block lets ~19 blocks/CU fit (r11's 5x32KB exact-fit
// failed; r14's regression was halved W-amortization, NOT small LDS — here
// rows/wave stays 32 so W-traffic is unchanged). (64,5) caps regs at 102 >= 64.
__global__ __launch_bounds__(64, 5)
void lap_mlp_kernel(const float* __restrict__ DATAX, const float* __restrict__ STAGX,
                    const int* __restrict__ cidx,
                    const float* __restrict__ b2, const float* __restrict__ b3,
                    const float* __restrict__ b4,
                    const short* __restrict__ W1f, const short* __restrict__ W2f,
                    const short* __restrict__ W3f, const short* __restrict__ W4f,
                    float* __restrict__ out)
{
  __shared__ short lds_h[32*128];    // 8 KB activations; rows XOR-swizzled (256B stride)
  const int lane = threadIdx.x;                 // 64-thread block = 1 wave
  const int pbase = blockIdx.x * 32;            // this wave's 32 points
  const int l31 = lane & 31;
  const int l15 = lane & 15;
  const int lk  = lane >> 4;

  // ---- gather: lanes 0-31 load coords for row l31 (lanes 32-63 idle here)
  float x0 = 0.f, x1 = 0.f, x2 = 0.f;
  if (lane < 32) {
    int p = pbase + l31;
    const float* sp;
    if (p < Bc) {
      sp = DATAX + 3*(size_t)cidx[p];
    } else {
      int q = p - Bc;
      int isNeig = (q >= 6*Bc) ? 1 : 0;
      if (isNeig) q -= 6*Bc;
      int b = q / 6, s = q - 6*b;              // compiler emits magic-mul
      int s5 = s + (s >= 1) + (s == 5);        // {0,1,2,3,4,5} -> {0,2,3,4,5,7}
      int i = cidx[b];
      int ix = i >> 14, iy = (i >> 7) & 127, iz = i & 127;
      int bx = (s5 >> 2) & 1, by = (s5 >> 1) & 1, bz = s5 & 1;
      int dx, dy, dz, hi;
      if (isNeig) { dx = 2*bx-1; dy = 2*by-1; dz = 2*bz-1; hi = NFULL-1; }
      else        { dx = bx-1;   dy = by-1;   dz = bz-1;   hi = NSTAG-1; }
      // reference uses reduced-grid strides (127*127, 127) for BOTH gathers
      int f = (ix+dx)*16129 + (iy+dy)*127 + (iz+dz);
      f = f < 0 ? 0 : (f > hi ? hi : f);
      sp = (isNeig ? DATAX : STAGX) + 3*(size_t)f;
    }
    x0 = sp[0]; x1 = sp[1]; x2 = sp[2];
  }

  const int r0 = l15, r1 = l15 + 16;
  const int swz0 = (r0 & 7) << 4, swz1 = (r1 & 7) << 4;

  // ---- layer 1 (MFMA): B-frags [x0,x1,x2,1] in k<4 of lk==0 lanes, else 0
  {
    float y0 = __shfl(x0, 16 + l15);   // row 16+l15's coords (from lanes 16-31)
    float y1 = __shfl(x1, 16 + l15);
    float y2 = __shfl(x2, 16 + l15);
    bf16x8_t xf0, xf1;
    #pragma unroll
    for (int u = 0; u < 8; ++u) { xf0[u] = (__bf16)0.f; xf1[u] = (__bf16)0.f; }
    if (lk == 0) {
      xf0[0] = (__bf16)x0; xf0[1] = (__bf16)x1; xf0[2] = (__bf16)x2; xf0[3] = (__bf16)1.f;
      xf1[0] = (__bf16)y0; xf1[1] = (__bf16)y1; xf1[2] = (__bf16)y2; xf1[3] = (__bf16)1.f;
    }
    const short* ap = W1f + lane*8;   // fragment ct at ap + ct*512 shorts
    #pragma unroll
    for (int ct = 0; ct < 8; ++ct) {
      bf16x8_t aw = *(const bf16x8_t*)(ap + ct*512);
      f32x4_t a0 = (f32x4_t){0.f,0.f,0.f,0.f};
      f32x4_t a1 = (f32x4_t){0.f,0.f,0.f,0.f};
      a0 = __builtin_amdgcn_mfma_f32_16x16x32_bf16(aw, xf0, a0, 0, 0, 0);
      a1 = __builtin_amdgcn_mfma_f32_16x16x32_bf16(aw, xf1, a1, 0, 0, 0);
      bf16x4_t hv0, hv1;
      #pragma unroll
      for (int u = 0; u < 4; ++u) { hv0[u] = (__bf16)fast_tanh(a0[u]); hv1[u] = (__bf16)fast_tanh(a1[u]); }
      *(bf16x4_t*)((char*)lds_h + r0*256 + ((ct*32 + lk*8) ^ swz0)) = hv0;
      *(bf16x4_t*)((char*)lds_h + r1*256 + ((ct*32 + lk*8) ^ swz1)) = hv1;
    }
  }
  // no barrier: per-wave DS ops are processed in order; reads below see this wave's writes

  // ---- layers 2,3 (MFMA, operand-swapped); Wf from global (L2-resident 32KB)
  auto gemm_layer = [&](const short* __restrict__ Wf, const float* __restrict__ bias){
    // hoist all h-fragments (snapshot REQUIRED: epilogue overwrites these rows)
    bf16x8_t afr[8];
    #pragma unroll
    for (int kk = 0; kk < 4; ++kk) {
      int kb = kk*64 + lk*16;
      afr[2*kk+0] = *(const bf16x8_t*)((char*)lds_h + r0*256 + (kb ^ swz0));
      afr[2*kk+1] = *(const bf16x8_t*)((char*)lds_h + r1*256 + (kb ^ swz1));
    }
    const short* bp = Wf + lane*8;   // fragment f = ct*4+kk at bp + f*512 shorts
    const f32x4_t* bias4 = (const f32x4_t*)bias;

    // ct-level double-buffer: cur[4] = ct's 4 kk-fragments (contiguous 4KB),
    // prefetched with its bias vector during the previous ct's MFMAs.
    bf16x8_t bA[4], bB[4];
    f32x4_t bvA, bvB;
    #pragma unroll
    for (int kk = 0; kk < 4; ++kk)
      bA[kk] = *(const bf16x8_t*)(bp + kk*512);
    bvA = bias4[lk];                 // bias[j], j = 0*16 + lk*4 + u

    auto ct_step = [&](int ct, bf16x8_t (&cur)[4], bf16x8_t (&nxt)[4],
                       f32x4_t& bvc, f32x4_t& bvn){
      if (ct < 7) {
        #pragma unroll
        for (int kk = 0; kk < 4; ++kk)
          nxt[kk] = *(const bf16x8_t*)(bp + ((ct+1)*4 + kk)*512);
        bvn = bias4[(ct+1)*4 + lk];
      }
      f32x4_t acc0 = bvc;            // C-in = bias (uniform across D-cols)
      f32x4_t acc1 = bvc;
      #pragma unroll
      for (int kk = 0; kk < 4; ++kk) {
        // D = Wf x h^T: D col(lane&15) = h-row m, D row(lk*4+u) = out col j
        acc0 = __builtin_amdgcn_mfma_f32_16x16x32_bf16(cur[kk], afr[2*kk+0], acc0, 0, 0, 0);
        acc1 = __builtin_amdgcn_mfma_f32_16x16x32_bf16(cur[kk], afr[2*kk+1], acc1, 0, 0, 0);
      }
      __builtin_amdgcn_sched_barrier(0);   // fence: ct+2 loads cannot hoist here
      // epilogue: tanh -> 4 packed bf16 = one 8B write per rt.
      // No fence after: epilogue (VALU) overlaps next ct's loads/MFMAs.
      {
        bf16x4_t hv;
        #pragma unroll
        for (int u = 0; u < 4; ++u) hv[u] = (__bf16)fast_tanh(acc0[u]);
        *(bf16x4_t*)((char*)lds_h + r0*256 + ((ct*32 + lk*8) ^ swz0)) = hv;
      }
      {
        bf16x4_t hv;
        #pragma unroll
        for (int u = 0; u < 4; ++u) hv[u] = (__bf16)fast_tanh(acc1[u]);
        *(bf16x4_t*)((char*)lds_h + r1*256 + ((ct*32 + lk*8) ^ swz1)) = hv;
      }
    };
    ct_step(0, bA, bB, bvA, bvB);
    ct_step(1, bB, bA, bvB, bvA);
    ct_step(2, bA, bB, bvA, bvB);
    ct_step(3, bB, bA, bvB, bvA);
    ct_step(4, bA, bB, bvA, bvB);
    ct_step(5, bB, bA, bvB, bvA);
    ct_step(6, bA, bB, bvA, bvB);
    ct_step(7, bB, bA, bvB, bvA);
  };
  gemm_layer(W2f, b2);
  gemm_layer(W3f, b3);

  // ---- layer 4 (MFMA): out = h3 @ W4 + b4.  W4f A-row 0 = W4[k]; h3-frags
  // re-read in B-layout (same addressing as afr). D[0][m] = lanes 0-15, elem 0.
  {
    bf16x8_t hfr[8];
    #pragma unroll
    for (int kk = 0; kk < 4; ++kk) {
      int kb = kk*64 + lk*16;
      hfr[2*kk+0] = *(const bf16x8_t*)((char*)lds_h + r0*256 + (kb ^ swz0));
      hfr[2*kk+1] = *(const bf16x8_t*)((char*)lds_h + r1*256 + (kb ^ swz1));
    }
    const short* wp4 = W4f + lane*8;   // fragment kk at wp4 + kk*512 shorts
    f32x4_t a0 = (f32x4_t){0.f,0.f,0.f,0.f};
    f32x4_t a1 = (f32x4_t){0.f,0.f,0.f,0.f};
    #pragma unroll
    for (int kk = 0; kk < 4; ++kk) {
      bf16x8_t w = *(const bf16x8_t*)(wp4 + kk*512);
      a0 = __builtin_amdgcn_mfma_f32_16x16x32_bf16(w, hfr[2*kk+0], a0, 0, 0, 0);
      a1 = __builtin_amdgcn_mfma_f32_16x16x32_bf16(w, hfr[2*kk+1], a1, 0, 0, 0);
    }
    if (lane < 16) {
      float bb = b4[0];
      out[pbase + l15]      = a0[0] + bb;
      out[pbase + 16 + l15] = a1[0] + bb;
    }
  }
}

// ---- per-center loss terms + deterministic block partials (no atomics)
// mlp layout: [0,Bc) center pred; [Bc,7Bc) stag x6; [7Bc,13Bc) neig x6,
// slot order si -> offset {0,2,3,4,5,7}.
__global__ __launch_bounds__(256)
void lap_reduce_kernel(const int* __restrict__ cidx, const float* __restrict__ DATAF,
                       const float* __restrict__ LAPLF, const float* __restrict__ mlp,
                       float* __restrict__ partials)
{
  int b = blockIdx.x * 256 + threadIdx.x;   // exactly Bc threads
  int i = cidx[b];
  int ix = i >> 14, iy = (i >> 7) & 127, iz = i & 127;
  bool interior = (ix >= 1) && (ix < 127) && (iy >= 1) && (iy < 127) && (iz >= 1) && (iz < 127);
  float e = fabsf(mlp[b] - DATAF[i]);
  const float* ps = mlp + Bc   + 6*(size_t)b;   // si: 0->o0,1->o2,2->o3,3->o4,4->o5,5->o7
  const float* pn = mlp + 7*Bc + 6*(size_t)b;
  auto term = [](float a, float bq, float c, float d){
    return fabsf(a + bq - c - d) / ((a + bq + c + d) * 1.5f);
  };
  float lap = term(pn[5], pn[0], ps[5], ps[0])    // o7,o0
            + term(pn[2], pn[3], ps[2], ps[3])    // o3,o4
            + term(pn[4], pn[1], ps[4], ps[1]);   // o5,o2
  float dl = LAPLF[i] - lap;
  float sq = interior ? dl*dl : 0.f;
  float cn = interior ? 1.f : 0.f;
  #pragma unroll
  for (int o = 32; o > 0; o >>= 1) {
    e  += __shfl_down(e, o);
    sq += __shfl_down(sq, o);
    cn += __shfl_down(cn, o);
  }
  __shared__ float sm[4][3];
  int w = threadIdx.x >> 6;
  if ((threadIdx.x & 63) == 0) { sm[w][0]=e; sm[w][1]=sq; sm[w][2]=cn; }
  __syncthreads();
  if (threadIdx.x == 0) {
    float se=0, ss=0, sc=0;
    #pragma unroll
    for (int k = 0; k < 4; ++k){ se+=sm[k][0]; ss+=sm[k][1]; sc+=sm[k][2]; }
    partials[blockIdx.x*4+0]=se; partials[blockIdx.x*4+1]=ss; partials[blockIdx.x*4+2]=sc;
  }
}

__global__ void lap_finalize_kernel(const float* __restrict__ partials, float* __restrict__ out){
  int l = threadIdx.x;   // 64 threads
  float se=0, ss=0, sc=0;
  for (int r = l; r < 128; r += 64) {
    se += partials[4*r+0]; ss += partials[4*r+1]; sc += partials[4*r+2];
  }
  #pragma unroll
  for (int o = 32; o > 0; o >>= 1) {
    se += __shfl_down(se, o); ss += __shfl_down(ss, o); sc += __shfl_down(sc, o);
  }
  if (l == 0) out[0] = se * (1.0f/32768.f) + ss / fmaxf(sc, 1.f);
}

extern "C" void kernel_launch(void* const* d_in, const int* in_sizes, int n_in,
                              void* d_out, int out_size, void* d_ws, size_t ws_size,
                              hipStream_t stream)
{
  const float* DATAX = (const float*)d_in[0];
  const float* DATAF = (const float*)d_in[1];
  const float* STAGX = (const float*)d_in[2];
  const float* LAPLF = (const float*)d_in[3];
  const float* W1    = (const float*)d_in[4];
  const float* b1    = (const float*)d_in[5];
  const float* W2    = (const float*)d_in[6];
  const float* b2    = (const float*)d_in[7];
  const float* W3    = (const float*)d_in[8];
  const float* b3    = (const float*)d_in[9];
  const float* W4    = (const float*)d_in[10];
  const float* b4    = (const float*)d_in[11];
  const int*   cidx  = (const int*)d_in[12];
  float* out = (float*)d_out;

  char* ws = (char*)d_ws;
  float* partials = (float*)ws;                 // 128*4 floats
  short* W1f      = (short*)(ws + 4096);        // 8 KB
  short* W2f      = (short*)(ws + 12288);       // 32 KB
  short* W3f      = (short*)(ws + 45056);       // 32 KB
  short* W4f      = (short*)(ws + 77824);       // 4 KB
  float* mlp_out  = (float*)(ws + 81920);       // 13*Bc floats (~1.7 MB)

  lap_convert_w<<<152, 256, 0, stream>>>(W1, b1, W2, W3, W4, W1f, W2f, W3f, W4f);
  lap_mlp_kernel<<<P_TOTAL/32, 64, 0, stream>>>(DATAX, STAGX, cidx,
                                                b2, b3, b4,
                                                W1f, W2f, W3f, W4f, mlp_out);
  lap_reduce_kernel<<<Bc/256, 256, 0, stream>>>(cidx, DATAF, LAPLF, mlp_out, partials);
  lap_finalize_kernel<<<1, 64, 0, stream>>>(partials, out);
}

// Round 21
// 64.516 us; speedup vs baseline: 1.2677x; 1.2677x over previous
//
#include <hip/hip_runtime.h>
#include <stdint.h>

#define Bc 32768
#define NSTAG 2048383
#define NFULL 2097152
#define P_TOTAL (13*Bc)   // 425984 = 3328 * 128 (only the 6+6 USED stencil points)

typedef short  short8_t __attribute__((ext_vector_type(8)));
typedef __bf16 bf16x8_t __attribute__((ext_vector_type(8)));
typedef __bf16 bf16x4_t __attribute__((ext_vector_type(4)));
typedef float  f32x4_t  __attribute__((ext_vector_type(4)));

#if __has_builtin(__builtin_amdgcn_exp2f)
#define EXP2F(x) __builtin_amdgcn_exp2f(x)
#else
#define EXP2F(x) exp2f(x)
#endif
#if __has_builtin(__builtin_amdgcn_rcpf)
#define RCPF(x) __builtin_amdgcn_rcpf(x)
#else
#define RCPF(x) (1.0f/(x))
#endif

// tanh(x) = 1 - 2/(e^{2x}+1); e^{2x} = 2^(x*2*log2 e). 5 insts, exact at +-inf.
__device__ __forceinline__ float fast_tanh(float x){
  float e = EXP2F(x * 2.885390081777927f);
  return fmaf(-2.0f, RCPF(e + 1.0f), 1.0f);
}

__device__ __forceinline__ short f2bf(float f){
  union { float f; unsigned u; } v; v.f = f;
  unsigned r = v.u + 0x7FFFu + ((v.u >> 16) & 1u);   // RNE
  return (short)(r >> 16);
}

// ---- weight convert to FRAGMENT-MAJOR bf16 (A-operand mapping):
// W2f/W3f CT-MAJOR: f = ct*4+kk, Wf[f*512 + lane*8 + u] = bf16(W[k][j]),
// j = ct*16+(lane&15), k = kk*32+(lane>>4)*8+u  (4 kk-frags of a ct contiguous).
// W1f: K=4 augmented ([W1;b1;0...], f=ct, 8 KB).  W4f: A-row 0 = W4[k], f=kk.
__global__ void lap_convert_w(const float* __restrict__ W1, const float* __restrict__ b1,
                              const float* __restrict__ W2, const float* __restrict__ W3,
                              const float* __restrict__ W4,
                              short* __restrict__ W1f, short* __restrict__ W2f,
                              short* __restrict__ W3f, short* __restrict__ W4f){
  int o = blockIdx.x * 256 + threadIdx.x;      // 0..38911
  if (o < 4096) {
    int e = o;
    int u = e & 7, lane = (e >> 3) & 63, ct = (e >> 9) & 7;
    int j = ct*16 + (lane & 15);
    int k = (lane >> 4)*8 + u;
    float v = (k < 3) ? W1[k*128 + j] : ((k == 3) ? b1[j] : 0.f);
    W1f[e] = f2bf(v);
  } else if (o < 36864) {
    o -= 4096;
    int which = o >> 14; int e = o & 16383;
    int u = e & 7, lane = (e >> 3) & 63, ct = (e >> 9) & 7, kk = e >> 12;
    int j = ct*16 + (lane & 15);
    int k = kk*32 + (lane >> 4)*8 + u;
    const float* W = which ? W3 : W2;
    short* O = which ? W3f : W2f;
    O[(ct*4 + kk)*512 + lane*8 + u] = f2bf(W[k*128 + j]);
  } else {
    int e = o - 36864;                          // 0..2047
    int u = e & 7, lane = (e >> 3) & 63, kk = e >> 9;
    int k = kk*32 + (lane >> 4)*8 + u;
    W4f[e] = ((lane & 15) == 0) ? f2bf(W4[k]) : 0;
  }
}

// ---- main MLP kernel: 128 points per block, 32 per wave, fully wave-private.
// r21 = r19 verbatim (best: 64.8 us). r20's 1-wave blocks regressed (allocator
// spill at (64,5) + occupancy stuck at 42% — workgroup-slot limited). 4 waves/
// SIMD is this structure's practical occupancy ceiling (r11/r14/r20 all failed).
__global__ __launch_bounds__(256, 4)
void lap_mlp_kernel(const float* __restrict__ DATAX, const float* __restrict__ STAGX,
                    const int* __restrict__ cidx,
                    const float* __restrict__ b2, const float* __restrict__ b3,
                    const float* __restrict__ b4,
                    const short* __restrict__ W1f, const short* __restrict__ W2f,
                    const short* __restrict__ W3f, const short* __restrict__ W4f,
                    float* __restrict__ out)
{
  __shared__ short lds_h[128*128];   // 32 KB activations; rows XOR-swizzled (256B stride)
  const int t    = threadIdx.x;
  const int lane = t & 63;
  const int wv   = t >> 6;
  const int rbase = wv * 32;                    // this wave's private 32 rows
  const int pbase = blockIdx.x * 128 + rbase;   // this wave's 32 points
  const int l31 = lane & 31;
  const int l15 = lane & 15;
  const int lk  = lane >> 4;

  // ---- gather: lanes 0-31 load coords for row l31 (lanes 32-63 idle here)
  float x0 = 0.f, x1 = 0.f, x2 = 0.f;
  if (lane < 32) {
    int p = pbase + l31;
    const float* sp;
    if (p < Bc) {
      sp = DATAX + 3*(size_t)cidx[p];
    } else {
      int q = p - Bc;
      int isNeig = (q >= 6*Bc) ? 1 : 0;
      if (isNeig) q -= 6*Bc;
      int b = q / 6, s = q - 6*b;              // compiler emits magic-mul
      int s5 = s + (s >= 1) + (s == 5);        // {0,1,2,3,4,5} -> {0,2,3,4,5,7}
      int i = cidx[b];
      int ix = i >> 14, iy = (i >> 7) & 127, iz = i & 127;
      int bx = (s5 >> 2) & 1, by = (s5 >> 1) & 1, bz = s5 & 1;
      int dx, dy, dz, hi;
      if (isNeig) { dx = 2*bx-1; dy = 2*by-1; dz = 2*bz-1; hi = NFULL-1; }
      else        { dx = bx-1;   dy = by-1;   dz = bz-1;   hi = NSTAG-1; }
      // reference uses reduced-grid strides (127*127, 127) for BOTH gathers
      int f = (ix+dx)*16129 + (iy+dy)*127 + (iz+dz);
      f = f < 0 ? 0 : (f > hi ? hi : f);
      sp = (isNeig ? DATAX : STAGX) + 3*(size_t)f;
    }
    x0 = sp[0]; x1 = sp[1]; x2 = sp[2];
  }

  const int r0 = rbase + l15, r1 = r0 + 16;
  const int swz0 = (r0 & 7) << 4, swz1 = (r1 & 7) << 4;

  // ---- layer 1 (MFMA): B-frags [x0,x1,x2,1] in k<4 of lk==0 lanes, else 0
  {
    float y0 = __shfl(x0, 16 + l15);   // row 16+l15's coords (from lanes 16-31)
    float y1 = __shfl(x1, 16 + l15);
    float y2 = __shfl(x2, 16 + l15);
    bf16x8_t xf0, xf1;
    #pragma unroll
    for (int u = 0; u < 8; ++u) { xf0[u] = (__bf16)0.f; xf1[u] = (__bf16)0.f; }
    if (lk == 0) {
      xf0[0] = (__bf16)x0; xf0[1] = (__bf16)x1; xf0[2] = (__bf16)x2; xf0[3] = (__bf16)1.f;
      xf1[0] = (__bf16)y0; xf1[1] = (__bf16)y1; xf1[2] = (__bf16)y2; xf1[3] = (__bf16)1.f;
    }
    const short* ap = W1f + lane*8;   // fragment ct at ap + ct*512 shorts
    #pragma unroll
    for (int ct = 0; ct < 8; ++ct) {
      bf16x8_t aw = *(const bf16x8_t*)(ap + ct*512);
      f32x4_t a0 = (f32x4_t){0.f,0.f,0.f,0.f};
      f32x4_t a1 = (f32x4_t){0.f,0.f,0.f,0.f};
      a0 = __builtin_amdgcn_mfma_f32_16x16x32_bf16(aw, xf0, a0, 0, 0, 0);
      a1 = __builtin_amdgcn_mfma_f32_16x16x32_bf16(aw, xf1, a1, 0, 0, 0);
      bf16x4_t hv0, hv1;
      #pragma unroll
      for (int u = 0; u < 4; ++u) { hv0[u] = (__bf16)fast_tanh(a0[u]); hv1[u] = (__bf16)fast_tanh(a1[u]); }
      *(bf16x4_t*)((char*)lds_h + r0*256 + ((ct*32 + lk*8) ^ swz0)) = hv0;
      *(bf16x4_t*)((char*)lds_h + r1*256 + ((ct*32 + lk*8) ^ swz1)) = hv1;
    }
  }
  // no barrier: per-wave DS ops are processed in order; reads below see this wave's writes

  // ---- layers 2,3 (MFMA, operand-swapped); Wf from global (L2-resident 32KB)
  auto gemm_layer = [&](const short* __restrict__ Wf, const float* __restrict__ bias){
    // hoist all h-fragments (snapshot REQUIRED: epilogue overwrites these rows)
    bf16x8_t afr[8];
    #pragma unroll
    for (int kk = 0; kk < 4; ++kk) {
      int kb = kk*64 + lk*16;
      afr[2*kk+0] = *(const bf16x8_t*)((char*)lds_h + r0*256 + (kb ^ swz0));
      afr[2*kk+1] = *(const bf16x8_t*)((char*)lds_h + r1*256 + (kb ^ swz1));
    }
    const short* bp = Wf + lane*8;   // fragment f = ct*4+kk at bp + f*512 shorts
    const f32x4_t* bias4 = (const f32x4_t*)bias;

    // ct-level double-buffer: cur[4] = ct's 4 kk-fragments (contiguous 4KB),
    // prefetched with its bias vector during the previous ct's MFMAs.
    bf16x8_t bA[4], bB[4];
    f32x4_t bvA, bvB;
    #pragma unroll
    for (int kk = 0; kk < 4; ++kk)
      bA[kk] = *(const bf16x8_t*)(bp + kk*512);
    bvA = bias4[lk];                 // bias[j], j = 0*16 + lk*4 + u

    auto ct_step = [&](int ct, bf16x8_t (&cur)[4], bf16x8_t (&nxt)[4],
                       f32x4_t& bvc, f32x4_t& bvn){
      if (ct < 7) {
        #pragma unroll
        for (int kk = 0; kk < 4; ++kk)
          nxt[kk] = *(const bf16x8_t*)(bp + ((ct+1)*4 + kk)*512);
        bvn = bias4[(ct+1)*4 + lk];
      }
      f32x4_t acc0 = bvc;            // C-in = bias (uniform across D-cols)
      f32x4_t acc1 = bvc;
      #pragma unroll
      for (int kk = 0; kk < 4; ++kk) {
        // D = Wf x h^T: D col(lane&15) = h-row m, D row(lk*4+u) = out col j
        acc0 = __builtin_amdgcn_mfma_f32_16x16x32_bf16(cur[kk], afr[2*kk+0], acc0, 0, 0, 0);
        acc1 = __builtin_amdgcn_mfma_f32_16x16x32_bf16(cur[kk], afr[2*kk+1], acc1, 0, 0, 0);
      }
      __builtin_amdgcn_sched_barrier(0);   // fence: ct+2 loads cannot hoist here
      // epilogue: tanh -> 4 packed bf16 = one 8B write per rt.
      // No fence after: epilogue (VALU) overlaps next ct's loads/MFMAs.
      {
        bf16x4_t hv;
        #pragma unroll
        for (int u = 0; u < 4; ++u) hv[u] = (__bf16)fast_tanh(acc0[u]);
        *(bf16x4_t*)((char*)lds_h + r0*256 + ((ct*32 + lk*8) ^ swz0)) = hv;
      }
      {
        bf16x4_t hv;
        #pragma unroll
        for (int u = 0; u < 4; ++u) hv[u] = (__bf16)fast_tanh(acc1[u]);
        *(bf16x4_t*)((char*)lds_h + r1*256 + ((ct*32 + lk*8) ^ swz1)) = hv;
      }
    };
    ct_step(0, bA, bB, bvA, bvB);
    ct_step(1, bB, bA, bvB, bvA);
    ct_step(2, bA, bB, bvA, bvB);
    ct_step(3, bB, bA, bvB, bvA);
    ct_step(4, bA, bB, bvA, bvB);
    ct_step(5, bB, bA, bvB, bvA);
    ct_step(6, bA, bB, bvA, bvB);
    ct_step(7, bB, bA, bvB, bvA);
  };
  gemm_layer(W2f, b2);
  gemm_layer(W3f, b3);

  // ---- layer 4 (MFMA): out = h3 @ W4 + b4.  W4f A-row 0 = W4[k]; h3-frags
  // re-read in B-layout (same addressing as afr). D[0][m] = lanes 0-15, elem 0.
  {
    bf16x8_t hfr[8];
    #pragma unroll
    for (int kk = 0; kk < 4; ++kk) {
      int kb = kk*64 + lk*16;
      hfr[2*kk+0] = *(const bf16x8_t*)((char*)lds_h + r0*256 + (kb ^ swz0));
      hfr[2*kk+1] = *(const bf16x8_t*)((char*)lds_h + r1*256 + (kb ^ swz1));
    }
    const short* wp4 = W4f + lane*8;   // fragment kk at wp4 + kk*512 shorts
    f32x4_t a0 = (f32x4_t){0.f,0.f,0.f,0.f};
    f32x4_t a1 = (f32x4_t){0.f,0.f,0.f,0.f};
    #pragma unroll
    for (int kk = 0; kk < 4; ++kk) {
      bf16x8_t w = *(const bf16x8_t*)(wp4 + kk*512);
      a0 = __builtin_amdgcn_mfma_f32_16x16x32_bf16(w, hfr[2*kk+0], a0, 0, 0, 0);
      a1 = __builtin_amdgcn_mfma_f32_16x16x32_bf16(w, hfr[2*kk+1], a1, 0, 0, 0);
    }
    if (lane < 16) {
      float bb = b4[0];
      out[pbase + l15]      = a0[0] + bb;
      out[pbase + 16 + l15] = a1[0] + bb;
    }
  }
}

// ---- per-center loss terms + deterministic block partials (no atomics)
// mlp layout: [0,Bc) center pred; [Bc,7Bc) stag x6; [7Bc,13Bc) neig x6,
// slot order si -> offset {0,2,3,4,5,7}.
__global__ __launch_bounds__(256)
void lap_reduce_kernel(const int* __restrict__ cidx, const float* __restrict__ DATAF,
                       const float* __restrict__ LAPLF, const float* __restrict__ mlp,
                       float* __restrict__ partials)
{
  int b = blockIdx.x * 256 + threadIdx.x;   // exactly Bc threads
  int i = cidx[b];
  int ix = i >> 14, iy = (i >> 7) & 127, iz = i & 127;
  bool interior = (ix >= 1) && (ix < 127) && (iy >= 1) && (iy < 127) && (iz >= 1) && (iz < 127);
  float e = fabsf(mlp[b] - DATAF[i]);
  const float* ps = mlp + Bc   + 6*(size_t)b;   // si: 0->o0,1->o2,2->o3,3->o4,4->o5,5->o7
  const float* pn = mlp + 7*Bc + 6*(size_t)b;
  auto term = [](float a, float bq, float c, float d){
    return fabsf(a + bq - c - d) / ((a + bq + c + d) * 1.5f);
  };
  float lap = term(pn[5], pn[0], ps[5], ps[0])    // o7,o0
            + term(pn[2], pn[3], ps[2], ps[3])    // o3,o4
            + term(pn[4], pn[1], ps[4], ps[1]);   // o5,o2
  float dl = LAPLF[i] - lap;
  float sq = interior ? dl*dl : 0.f;
  float cn = interior ? 1.f : 0.f;
  #pragma unroll
  for (int o = 32; o > 0; o >>= 1) {
    e  += __shfl_down(e, o);
    sq += __shfl_down(sq, o);
    cn += __shfl_down(cn, o);
  }
  __shared__ float sm[4][3];
  int w = threadIdx.x >> 6;
  if ((threadIdx.x & 63) == 0) { sm[w][0]=e; sm[w][1]=sq; sm[w][2]=cn; }
  __syncthreads();
  if (threadIdx.x == 0) {
    float se=0, ss=0, sc=0;
    #pragma unroll
    for (int k = 0; k < 4; ++k){ se+=sm[k][0]; ss+=sm[k][1]; sc+=sm[k][2]; }
    partials[blockIdx.x*4+0]=se; partials[blockIdx.x*4+1]=ss; partials[blockIdx.x*4+2]=sc;
  }
}

__global__ void lap_finalize_kernel(const float* __restrict__ partials, float* __restrict__ out){
  int l = threadIdx.x;   // 64 threads
  float se=0, ss=0, sc=0;
  for (int r = l; r < 128; r += 64) {
    se += partials[4*r+0]; ss += partials[4*r+1]; sc += partials[4*r+2];
  }
  #pragma unroll
  for (int o = 32; o > 0; o >>= 1) {
    se += __shfl_down(se, o); ss += __shfl_down(ss, o); sc += __shfl_down(sc, o);
  }
  if (l == 0) out[0] = se * (1.0f/32768.f) + ss / fmaxf(sc, 1.f);
}

extern "C" void kernel_launch(void* const* d_in, const int* in_sizes, int n_in,
                              void* d_out, int out_size, void* d_ws, size_t ws_size,
                              hipStream_t stream)
{
  const float* DATAX = (const float*)d_in[0];
  const float* DATAF = (const float*)d_in[1];
  const float* STAGX = (const float*)d_in[2];
  const float* LAPLF = (const float*)d_in[3];
  const float* W1    = (const float*)d_in[4];
  const float* b1    = (const float*)d_in[5];
  const float* W2    = (const float*)d_in[6];
  const float* b2    = (const float*)d_in[7];
  const float* W3    = (const float*)d_in[8];
  const float* b3    = (const float*)d_in[9];
  const float* W4    = (const float*)d_in[10];
  const float* b4    = (const float*)d_in[11];
  const int*   cidx  = (const int*)d_in[12];
  float* out = (float*)d_out;

  char* ws = (char*)d_ws;
  float* partials = (float*)ws;                 // 128*4 floats
  short* W1f      = (short*)(ws + 4096);        // 8 KB
  short* W2f      = (short*)(ws + 12288);       // 32 KB
  short* W3f      = (short*)(ws + 45056);       // 32 KB
  short* W4f      = (short*)(ws + 77824);       // 4 KB
  float* mlp_out  = (float*)(ws + 81920);       // 13*Bc floats (~1.7 MB)

  lap_convert_w<<<152, 256, 0, stream>>>(W1, b1, W2, W3, W4, W1f, W2f, W3f, W4f);
  lap_mlp_kernel<<<P_TOTAL/128, 256, 0, stream>>>(DATAX, STAGX, cidx,
                                                  b2, b3, b4,
                                                  W1f, W2f, W3f, W4f, mlp_out);
  lap_reduce_kernel<<<Bc/256, 256, 0, stream>>>(cidx, DATAF, LAPLF, mlp_out, partials);
  lap_finalize_kernel<<<1, 64, 0, stream>>>(partials, out);
}